// Round 6
// baseline (230.972 us; speedup 1.0000x reference)
//
#include <hip/hip_runtime.h>
#include <hip/hip_fp16.h>

#define N_NODES 50000
#define N_EDGES 800000
#define N_GRAPHS 64

#define CAP 64            // fixed-stride CSR row capacity; P(deg>=64) ~ 1e-13 on Poisson(16)
#define HALF_N 25000      // lo/hi source split: each half of h = 3.2MB -> fits 4MB XCD L2
#define FILL_STRIPES 256  // blocks per node-range; grid = 8*FILL_STRIPES

struct __align__(8) h4v { __half2 a, b; };   // 4 fp16 features = 8 B

// ---------------- init + edge pack + W2->fp16 ----------------
// pk[e] = (dst<<16)|src : both < 50000 < 65536. One 4B read/edge downstream.

__global__ void k_zero_pack(unsigned* __restrict__ cnt, float* __restrict__ sums,
                            const int* __restrict__ src, const int* __restrict__ dst,
                            unsigned* __restrict__ pk,
                            const float* __restrict__ W2, __half* __restrict__ w2h) {
    int i = blockIdx.x * 256 + threadIdx.x;
    if (i < N_NODES) cnt[i] = 0;
    if (i < N_GRAPHS * 128) sums[i] = 0.f;
    if (i < 64 * 128) w2h[i] = __float2half_rn(W2[i]);
    if (i < N_EDGES) pk[i] = ((unsigned)dst[i] << 16) | (unsigned)src[i];
}

// ---------------- CSR build: ONE pass, split rows (lo from front, hi from back) ----------------
// cnt[d] packs two 16-bit counters (lo | hi<<16). Atomic returns are totally
// ordered per node, so writes with c_lo+c_hi < CAP occupy disjoint slots:
// lo at [0,L), hi at (CAP-1-H, CAP-1]. XCD-partitioned (R6 win).

__global__ void k_fill_direct(const unsigned* __restrict__ pk, unsigned* __restrict__ cnt,
                              unsigned short* __restrict__ csr, int E) {
    const int range = blockIdx.x & 7;
    const int stripe = blockIdx.x >> 3;
    const unsigned lo = range * (N_NODES / 8);
    const unsigned hi = lo + (N_NODES / 8);
    for (int e = stripe * 256 + threadIdx.x; e < E; e += FILL_STRIPES * 256) {
        unsigned p = pk[e];
        unsigned d = p >> 16;
        if (d >= lo && d < hi) {
            unsigned s = p & 0xffffu;
            bool isLo = s < HALF_N;
            unsigned old = atomicAdd(&cnt[d], isLo ? 1u : (1u << 16));
            unsigned c_lo = old & 0xffffu, c_hi = old >> 16;
            if (c_lo + c_hi < CAP) {
                unsigned slot = isLo ? c_lo : (CAP - 1 - c_hi);
                csr[(size_t)d * CAP + slot] = (unsigned short)s;
            }
        }
    }
}

__device__ __forceinline__ int deg_of(unsigned cw, int* clo_out, int* chi_out) {
    int clo = min((int)(cw & 0xffffu), CAP);
    int chi = min((int)(cw >> 16), CAP - clo);
    *clo_out = clo; *chi_out = chi;
    return clo + chi;
}

// ---------------- GEMM1: g̃(fp16) = dinv ⊙ (x @ W1) ----------------

__global__ __launch_bounds__(256) void k_gemm1(const float* __restrict__ A,
                                               const float* __restrict__ W,
                                               const unsigned* __restrict__ cnt,
                                               __half* __restrict__ Cout, int N) {
    const int FIN = 128;
    __shared__ __align__(16) float As[64 * (FIN + 2)];
    __shared__ __align__(16) float Wsm[FIN * 64];
    const int t = threadIdx.x;
    const int row0 = blockIdx.x * 64;

    const int NF4 = 64 * FIN / 4;
    for (int idx = t; idx < NF4; idx += 256) {
        int r = idx / (FIN / 4);
        int c4 = idx % (FIN / 4);
        float4 v = make_float4(0.f, 0.f, 0.f, 0.f);
        if (row0 + r < N) v = ((const float4*)(A + (size_t)(row0 + r) * FIN))[c4];
        float* p = &As[r * (FIN + 2) + c4 * 4];
        ((float2*)p)[0] = make_float2(v.x, v.y);
        ((float2*)p)[1] = make_float2(v.z, v.w);
    }
    for (int idx = t; idx < FIN * 16; idx += 256) {
        int r = idx / 16, c4 = idx % 16;
        *((float4*)&Wsm[r * 64 + c4 * 4]) = ((const float4*)(W + (size_t)r * 64))[c4];
    }
    __syncthreads();

    const int tc = (t & 15) * 4;
    const int tr = (t >> 4) * 4;
    float acc[4][4] = {};
#pragma unroll 4
    for (int k = 0; k < FIN; k += 2) {
        float2 a[4];
#pragma unroll
        for (int r = 0; r < 4; ++r)
            a[r] = *(const float2*)&As[(tr + r) * (FIN + 2) + k];
        float4 w0 = *(const float4*)&Wsm[k * 64 + tc];
        float4 w1 = *(const float4*)&Wsm[(k + 1) * 64 + tc];
#pragma unroll
        for (int r = 0; r < 4; ++r) {
            acc[r][0] = fmaf(a[r].x, w0.x, acc[r][0]);
            acc[r][1] = fmaf(a[r].x, w0.y, acc[r][1]);
            acc[r][2] = fmaf(a[r].x, w0.z, acc[r][2]);
            acc[r][3] = fmaf(a[r].x, w0.w, acc[r][3]);
            acc[r][0] = fmaf(a[r].y, w1.x, acc[r][0]);
            acc[r][1] = fmaf(a[r].y, w1.y, acc[r][1]);
            acc[r][2] = fmaf(a[r].y, w1.z, acc[r][2]);
            acc[r][3] = fmaf(a[r].y, w1.w, acc[r][3]);
        }
    }

#pragma unroll
    for (int r = 0; r < 4; ++r) {
        int row = row0 + tr + r;
        if (row < N) {
            int clo, chi;
            float s = rsqrtf((float)(deg_of(cnt[row], &clo, &chi) + 1));
            __half2* dsth = (__half2*)(Cout + (size_t)row * 64 + tc);
            dsth[0] = __floats2half2_rn(acc[r][0] * s, acc[r][1] * s);
            dsth[1] = __floats2half2_rn(acc[r][2] * s, acc[r][3] * s);
        }
    }
}

// ---------------- aggregates: 16 lanes/node, 8 B per lane, 0 LDS ----------------
// h pre-scaled by dinv. Max-occupancy gather (R2 lesson: fusing into LDS-heavy
// GEMM cost +23 µs). Two source phases: lo (h[0..25k) = 3.2MB, L2-resident)
// then hi (h[25k..50k)) — all resident waves stay in one 3.2MB half at a time.

template <bool RELU>
__global__ void k_agg(const h4v* __restrict__ h, const unsigned* __restrict__ cnt,
                      const unsigned short* __restrict__ csr,
                      const float* __restrict__ bias, h4v* __restrict__ out, int N) {
    int node = blockIdx.x * 16 + (threadIdx.x >> 4);
    int lane = threadIdx.x & 15;
    if (node >= N) return;
    int clo, chi;
    int deg = deg_of(cnt[node], &clo, &chi);
    float di = rsqrtf((float)(deg + 1));
    h4v sv = h[(size_t)node * 16 + lane];  // self loop (pre-scaled)
    float2 pa = __half22float2(sv.a), pb = __half22float2(sv.b);
    float x0 = pa.x, y0 = pa.y, z0 = pb.x, w0 = pb.y;
    float x1 = 0, y1 = 0, z1 = 0, w1 = 0;
    float x2 = 0, y2 = 0, z2 = 0, w2 = 0;
    float x3 = 0, y3 = 0, z3 = 0, w3 = 0;
    const unsigned short* row = csr + (size_t)node * CAP;

    // ---- phase A: lo sources, slots [0, clo) ----
    int j = 0;
    for (; j + 4 <= clo; j += 4) {
        ushort4 s4 = *(const ushort4*)(row + j);
        h4v v0 = h[(size_t)s4.x * 16 + lane];
        h4v v1 = h[(size_t)s4.y * 16 + lane];
        h4v v2 = h[(size_t)s4.z * 16 + lane];
        h4v v3 = h[(size_t)s4.w * 16 + lane];
        float2 a0 = __half22float2(v0.a), b0 = __half22float2(v0.b);
        float2 a1 = __half22float2(v1.a), b1 = __half22float2(v1.b);
        float2 a2 = __half22float2(v2.a), b2 = __half22float2(v2.b);
        float2 a3 = __half22float2(v3.a), b3 = __half22float2(v3.b);
        x0 += a0.x; y0 += a0.y; z0 += b0.x; w0 += b0.y;
        x1 += a1.x; y1 += a1.y; z1 += b1.x; w1 += b1.y;
        x2 += a2.x; y2 += a2.y; z2 += b2.x; w2 += b2.y;
        x3 += a3.x; y3 += a3.y; z3 += b3.x; w3 += b3.y;
    }
    for (; j < clo; ++j) {
        h4v v = h[(size_t)row[j] * 16 + lane];
        float2 a = __half22float2(v.a), b = __half22float2(v.b);
        x0 += a.x; y0 += a.y; z0 += b.x; w0 += b.y;
    }

    // ---- phase B: hi sources, slots [CAP-chi, CAP) ----
    j = CAP - chi;
    for (; (j & 3) && j < CAP; ++j) {
        h4v v = h[(size_t)row[j] * 16 + lane];
        float2 a = __half22float2(v.a), b = __half22float2(v.b);
        x0 += a.x; y0 += a.y; z0 += b.x; w0 += b.y;
    }
    for (; j + 4 <= CAP; j += 4) {
        ushort4 s4 = *(const ushort4*)(row + j);
        h4v v0 = h[(size_t)s4.x * 16 + lane];
        h4v v1 = h[(size_t)s4.y * 16 + lane];
        h4v v2 = h[(size_t)s4.z * 16 + lane];
        h4v v3 = h[(size_t)s4.w * 16 + lane];
        float2 a0 = __half22float2(v0.a), b0 = __half22float2(v0.b);
        float2 a1 = __half22float2(v1.a), b1 = __half22float2(v1.b);
        float2 a2 = __half22float2(v2.a), b2 = __half22float2(v2.b);
        float2 a3 = __half22float2(v3.a), b3 = __half22float2(v3.b);
        x0 += a0.x; y0 += a0.y; z0 += b0.x; w0 += b0.y;
        x1 += a1.x; y1 += a1.y; z1 += b1.x; w1 += b1.y;
        x2 += a2.x; y2 += a2.y; z2 += b2.x; w2 += b2.y;
        x3 += a3.x; y3 += a3.y; z3 += b3.x; w3 += b3.y;
    }

    float sx = (x0 + x1) + (x2 + x3);
    float sy = (y0 + y1) + (y2 + y3);
    float sz = (z0 + z1) + (z2 + z3);
    float sw = (w0 + w1) + (w2 + w3);
    h4v o;
    if (RELU) {
        float4 bv = ((const float4*)bias)[lane];
        float vx = fmaf(sx, di, bv.x); vx = vx > 0.f ? vx : 0.f;
        float vy = fmaf(sy, di, bv.y); vy = vy > 0.f ? vy : 0.f;
        float vz = fmaf(sz, di, bv.z); vz = vz > 0.f ? vz : 0.f;
        float vw = fmaf(sw, di, bv.w); vw = vw > 0.f ? vw : 0.f;
        o.a = __floats2half2_rn(di * vx, di * vy);
        o.b = __floats2half2_rn(di * vz, di * vw);
    } else {
        o.a = __floats2half2_rn(sx * di, sy * di);
        o.b = __floats2half2_rn(sz * di, sw * di);
    }
    out[(size_t)node * 16 + lane] = o;
}

// ---------------- GEMM2 + mean-pool, single pass over full 128 cols ----------------
// Reads z̃ ONCE; W2 fp16 in LDS (16KB) makes the full-width tile fit.

__global__ __launch_bounds__(256) void k_gemm_pool128(
    const __half2* __restrict__ A2,    // z̃ [N][32] half2
    const __half2* __restrict__ w2h,   // [64][64] half2 = [64][128] halves
    const float* __restrict__ bias,    // b2[128]
    const int* __restrict__ batch,
    float* __restrict__ sums, int N) {
    __shared__ __align__(16) float As[64 * 66];
    __shared__ __align__(16) __half2 Wh[64 * 64];   // 16 KB
    __shared__ float red[8][132];
    __shared__ int batchLDS[64];
    const int t = threadIdx.x;
    const int row0 = blockIdx.x * 64;

    for (int idx = t; idx < 4096; idx += 256) Wh[idx] = w2h[idx];
    if (t < 64) batchLDS[t] = batch[min(row0 + t, N - 1)];
    for (int idx = t; idx < 64 * 32; idx += 256) {
        int r = idx >> 5, c2 = idx & 31;
        float2 v = make_float2(0.f, 0.f);
        if (row0 + r < N) v = __half22float2(A2[(size_t)(row0 + r) * 32 + c2]);
        *(float2*)&As[r * 66 + c2 * 2] = v;
    }
    __syncthreads();

    const int tc = (t & 31) * 4;   // 0..124
    const int tr = (t >> 5) * 8;   // 0..56
    float acc[8][4] = {};
#pragma unroll 4
    for (int k = 0; k < 64; k += 2) {
        float2 a[8];
#pragma unroll
        for (int r = 0; r < 8; ++r)
            a[r] = *(const float2*)&As[(tr + r) * 66 + k];
        h4v wv0 = *(const h4v*)&Wh[k * 64 + (tc >> 1)];
        h4v wv1 = *(const h4v*)&Wh[(k + 1) * 64 + (tc >> 1)];
        float2 w00 = __half22float2(wv0.a), w01 = __half22float2(wv0.b);
        float2 w10 = __half22float2(wv1.a), w11 = __half22float2(wv1.b);
#pragma unroll
        for (int r = 0; r < 8; ++r) {
            acc[r][0] = fmaf(a[r].x, w00.x, acc[r][0]);
            acc[r][1] = fmaf(a[r].x, w00.y, acc[r][1]);
            acc[r][2] = fmaf(a[r].x, w01.x, acc[r][2]);
            acc[r][3] = fmaf(a[r].x, w01.y, acc[r][3]);
            acc[r][0] = fmaf(a[r].y, w10.x, acc[r][0]);
            acc[r][1] = fmaf(a[r].y, w10.y, acc[r][1]);
            acc[r][2] = fmaf(a[r].y, w11.x, acc[r][2]);
            acc[r][3] = fmaf(a[r].y, w11.y, acc[r][3]);
        }
    }

    float4 bv = *(const float4*)&bias[tc];
    float v[8][4];
#pragma unroll
    for (int r = 0; r < 8; ++r) {
        bool valid = (row0 + tr + r) < N;
        v[r][0] = valid ? fmaxf(acc[r][0] + bv.x, 0.f) : 0.f;
        v[r][1] = valid ? fmaxf(acc[r][1] + bv.y, 0.f) : 0.f;
        v[r][2] = valid ? fmaxf(acc[r][2] + bv.z, 0.f) : 0.f;
        v[r][3] = valid ? fmaxf(acc[r][3] + bv.w, 0.f) : 0.f;
    }

    const int g0 = batchLDS[0], g1 = batchLDS[63];
    const int rg = t >> 5;
    for (int g = g0; g <= g1; ++g) {
        float p0 = 0.f, p1 = 0.f, p2 = 0.f, p3 = 0.f;
#pragma unroll
        for (int r = 0; r < 8; ++r) {
            if (batchLDS[tr + r] == g) { p0 += v[r][0]; p1 += v[r][1]; p2 += v[r][2]; p3 += v[r][3]; }
        }
        red[rg][tc + 0] = p0; red[rg][tc + 1] = p1;
        red[rg][tc + 2] = p2; red[rg][tc + 3] = p3;
        __syncthreads();
        for (int off = 4; off > 0; off >>= 1) {
            if (rg < off) {
#pragma unroll
                for (int c = 0; c < 4; ++c) red[rg][tc + c] += red[rg + off][tc + c];
            }
            __syncthreads();
        }
        if (rg == 0) {
#pragma unroll
            for (int c = 0; c < 4; ++c)
                atomicAdd(&sums[g * 128 + tc + c], red[0][tc + c]);
        }
        __syncthreads();
    }
}

// ---------------- MLP head: one block per graph (cnt via binary search) ----------------

__global__ void k_mlp(const float* __restrict__ sums, const int* __restrict__ batch, int N,
                      const float* __restrict__ M1, const float* __restrict__ c1,
                      const float* __restrict__ M2, const float* __restrict__ c2,
                      const float* __restrict__ M3, const float* __restrict__ c3,
                      const float* __restrict__ M4, const float* __restrict__ c4,
                      float* __restrict__ out) {
    __shared__ float g[128], t1[64], t2[64], t3[64];
    __shared__ float cntb;
    int b = blockIdx.x;
    int t = threadIdx.x;
    if (t == 0) {
        int lo = 0, hi = N;
        while (lo < hi) { int m = (lo + hi) >> 1; if (batch[m] < b) lo = m + 1; else hi = m; }
        int lb = lo;
        lo = 0; hi = N;
        while (lo < hi) { int m = (lo + hi) >> 1; if (batch[m] <= b) lo = m + 1; else hi = m; }
        cntb = fmaxf((float)(lo - lb), 1.0f);
    }
    __syncthreads();
    if (t < 128) g[t] = sums[b * 128 + t] / cntb;
    __syncthreads();
    if (t < 64) {
        float acc = c1[t];
        for (int k = 0; k < 128; ++k) acc = fmaf(g[k], M1[k * 64 + t], acc);
        t1[t] = acc >= 0.f ? acc : 0.2f * acc;
    }
    __syncthreads();
    if (t < 64) {
        float acc = c2[t];
        for (int k = 0; k < 64; ++k) acc = fmaf(t1[k], M2[k * 64 + t], acc);
        t2[t] = acc >= 0.f ? acc : 0.1f * acc;
    }
    __syncthreads();
    if (t < 64) {
        float acc = c3[t];
        for (int k = 0; k < 64; ++k) acc = fmaf(t2[k], M3[k * 64 + t], acc);
        t3[t] = acc >= 0.f ? acc : 0.1f * acc;
    }
    __syncthreads();
    if (t == 0) {
        float acc = c4[0];
        for (int k = 0; k < 64; ++k) acc = fmaf(t3[k], M4[k], acc);
        out[b] = fmaxf(acc, 0.f);
    }
}

// ---------------- launch ----------------

extern "C" void kernel_launch(void* const* d_in, const int* in_sizes, int n_in,
                              void* d_out, int out_size, void* d_ws, size_t ws_size,
                              hipStream_t stream) {
    const float* x   = (const float*)d_in[0];
    const int*   ei  = (const int*)d_in[1];
    const int*   bat = (const int*)d_in[2];
    const float* W1  = (const float*)d_in[3];
    const float* b1  = (const float*)d_in[4];
    const float* W2  = (const float*)d_in[5];
    const float* b2  = (const float*)d_in[6];
    const float* M1  = (const float*)d_in[7];
    const float* c1  = (const float*)d_in[8];
    const float* M2  = (const float*)d_in[9];
    const float* c2  = (const float*)d_in[10];
    const float* M3  = (const float*)d_in[11];
    const float* c3  = (const float*)d_in[12];
    const float* M4  = (const float*)d_in[13];
    const float* c4  = (const float*)d_in[14];
    float* out = (float*)d_out;

    const int* src = ei;            // edge_index[0]
    const int* dst = ei + N_EDGES;  // edge_index[1]

    // workspace layout
    float* bufA    = (float*)d_ws;                          // g̃ / z̃: N*64 fp16
    float* bufB    = bufA + (size_t)N_NODES * 64;           // h̃1: N*64 fp16
    float* sums    = bufB + (size_t)N_NODES * 64;           // 64*128 f
    unsigned* cnt  = (unsigned*)(sums + N_GRAPHS * 128);    // N u32 (lo|hi<<16 counters)
    unsigned short* csr = (unsigned short*)(cnt + N_NODES); // N*CAP u16 (split rows)
    unsigned* pk   = (unsigned*)(csr + (size_t)N_NODES * CAP); // E u32 packed edges
    __half* w2h    = (__half*)(pk + N_EDGES);               // 64*128 fp16

    // ---- init + pack; ONE-pass split-row CSR build ----
    k_zero_pack<<<(N_EDGES + 255) / 256, 256, 0, stream>>>(cnt, sums, src, dst, pk, W2, w2h);
    k_fill_direct<<<8 * FILL_STRIPES, 256, 0, stream>>>(pk, cnt, csr, N_EDGES);

    const int NBLK = (N_NODES + 63) / 64;   // 782
    const int ABLK = (N_NODES + 15) / 16;   // 3125

    // ---- conv1: g̃(fp16) = dinv ⊙ (x@W1); h̃1(fp16) = dinv ⊙ relu(Â-sum + b1) ----
    k_gemm1<<<NBLK, 256, 0, stream>>>(x, W1, cnt, (__half*)bufA, N_NODES);
    k_agg<true><<<ABLK, 256, 0, stream>>>(
        (const h4v*)bufA, cnt, csr, b1, (h4v*)bufB, N_NODES);

    // ---- conv2: z̃(fp16) = dinv ⊙ (Σ h̃1); single-pass gemm2+relu+mean-pool ----
    k_agg<false><<<ABLK, 256, 0, stream>>>(
        (const h4v*)bufB, cnt, csr, nullptr, (h4v*)bufA, N_NODES);
    k_gemm_pool128<<<NBLK, 256, 0, stream>>>(
        (const __half2*)bufA, (const __half2*)w2h, b2, bat, sums, N_NODES);

    // ---- MLP ----
    k_mlp<<<N_GRAPHS, 128, 0, stream>>>(sums, bat, N_NODES,
                                        M1, c1, M2, c2, M3, c3, M4, c4, out);
}

// Round 7
// 224.020 us; speedup vs baseline: 1.0310x; 1.0310x over previous
//
#include <hip/hip_runtime.h>
#include <hip/hip_fp16.h>

#define N_NODES 50000
#define N_EDGES 800000
#define N_GRAPHS 64

#define CAP 64            // fixed-stride CSR row capacity; P(deg>=64) ~ 1e-13 on Poisson(16)
#define FILL_STRIPES 256  // blocks per node-range; grid = 8*FILL_STRIPES

struct __align__(8) h4v { __half2 a, b; };      // 4 fp16 features = 8 B
struct __align__(16) us8 { ushort4 a, b; };     // 8 csr indices = 16 B

// ---------------- init + edge pack + W2->fp16 ----------------
// pk[e] = (dst<<16)|src : both < 50000 < 65536. One 4B read/edge downstream.

__global__ void k_zero_pack(int* __restrict__ cnt, float* __restrict__ sums,
                            const int* __restrict__ src, const int* __restrict__ dst,
                            unsigned* __restrict__ pk,
                            const float* __restrict__ W2, __half* __restrict__ w2h) {
    int i = blockIdx.x * 256 + threadIdx.x;
    if (i < N_NODES) cnt[i] = 0;
    if (i < N_GRAPHS * 128) sums[i] = 0.f;
    if (i < 64 * 128) w2h[i] = __float2half_rn(W2[i]);
    if (i < N_EDGES) pk[i] = ((unsigned)dst[i] << 16) | (unsigned)src[i];
}

// ---------------- CSR build: ONE pass (fixed-stride rows) ----------------
// slot = atomicAdd(cnt[d]) doubles as degree count. XCD-partitioned:
// cnt lines and csr row destinations stay XCD-local.

__global__ void k_fill_direct(const unsigned* __restrict__ pk, int* __restrict__ cnt,
                              unsigned short* __restrict__ csr, int E) {
    const int range = blockIdx.x & 7;
    const int stripe = blockIdx.x >> 3;
    const unsigned lo = range * (N_NODES / 8);
    const unsigned hi = lo + (N_NODES / 8);
    for (int e = stripe * 256 + threadIdx.x; e < E; e += FILL_STRIPES * 256) {
        unsigned p = pk[e];
        unsigned d = p >> 16;
        if (d >= lo && d < hi) {
            int slot = atomicAdd(&cnt[d], 1);
            if (slot < CAP) csr[(size_t)d * CAP + slot] = (unsigned short)(p & 0xffffu);
        }
    }
}

// ---------------- GEMM1: g̃(fp16) = dinv ⊙ (x @ W1) ----------------
// dinv computed on the fly from cnt (rsqrt of degree+1).

__global__ __launch_bounds__(256) void k_gemm1(const float* __restrict__ A,
                                               const float* __restrict__ W,
                                               const int* __restrict__ cnt,
                                               __half* __restrict__ Cout, int N) {
    const int FIN = 128;
    __shared__ __align__(16) float As[64 * (FIN + 2)];
    __shared__ __align__(16) float Wsm[FIN * 64];
    const int t = threadIdx.x;
    const int row0 = blockIdx.x * 64;

    const int NF4 = 64 * FIN / 4;
    for (int idx = t; idx < NF4; idx += 256) {
        int r = idx / (FIN / 4);
        int c4 = idx % (FIN / 4);
        float4 v = make_float4(0.f, 0.f, 0.f, 0.f);
        if (row0 + r < N) v = ((const float4*)(A + (size_t)(row0 + r) * FIN))[c4];
        float* p = &As[r * (FIN + 2) + c4 * 4];
        ((float2*)p)[0] = make_float2(v.x, v.y);
        ((float2*)p)[1] = make_float2(v.z, v.w);
    }
    for (int idx = t; idx < FIN * 16; idx += 256) {
        int r = idx / 16, c4 = idx % 16;
        *((float4*)&Wsm[r * 64 + c4 * 4]) = ((const float4*)(W + (size_t)r * 64))[c4];
    }
    __syncthreads();

    const int tc = (t & 15) * 4;
    const int tr = (t >> 4) * 4;
    float acc[4][4] = {};
#pragma unroll 4
    for (int k = 0; k < FIN; k += 2) {
        float2 a[4];
#pragma unroll
        for (int r = 0; r < 4; ++r)
            a[r] = *(const float2*)&As[(tr + r) * (FIN + 2) + k];
        float4 w0 = *(const float4*)&Wsm[k * 64 + tc];
        float4 w1 = *(const float4*)&Wsm[(k + 1) * 64 + tc];
#pragma unroll
        for (int r = 0; r < 4; ++r) {
            acc[r][0] = fmaf(a[r].x, w0.x, acc[r][0]);
            acc[r][1] = fmaf(a[r].x, w0.y, acc[r][1]);
            acc[r][2] = fmaf(a[r].x, w0.z, acc[r][2]);
            acc[r][3] = fmaf(a[r].x, w0.w, acc[r][3]);
            acc[r][0] = fmaf(a[r].y, w1.x, acc[r][0]);
            acc[r][1] = fmaf(a[r].y, w1.y, acc[r][1]);
            acc[r][2] = fmaf(a[r].y, w1.z, acc[r][2]);
            acc[r][3] = fmaf(a[r].y, w1.w, acc[r][3]);
        }
    }

#pragma unroll
    for (int r = 0; r < 4; ++r) {
        int row = row0 + tr + r;
        if (row < N) {
            float s = rsqrtf((float)(min(cnt[row], CAP) + 1));
            __half2* dsth = (__half2*)(Cout + (size_t)row * 64 + tc);
            dsth[0] = __floats2half2_rn(acc[r][0] * s, acc[r][1] * s);
            dsth[1] = __floats2half2_rn(acc[r][2] * s, acc[r][3] * s);
        }
    }
}

// ---------------- aggregates: 16 lanes/node, 8 B per lane, 0 LDS ----------------
// h pre-scaled by dinv. Max-occupancy gather (R2 lesson: fusing into LDS-heavy
// GEMM cost +23 µs; R6 lesson: L2-phasing neutral -> latency-bound, not LLC-BW).
// Unroll-8: one ushort8 index load feeds 8 h-row loads in flight per lane
// (2x memory-level parallelism at constant occupancy).

template <bool RELU>
__global__ void k_agg(const h4v* __restrict__ h, const int* __restrict__ cnt,
                      const unsigned short* __restrict__ csr,
                      const float* __restrict__ bias, h4v* __restrict__ out, int N) {
    int node = blockIdx.x * 16 + (threadIdx.x >> 4);
    int lane = threadIdx.x & 15;
    if (node >= N) return;
    int c = min(cnt[node], CAP);
    float di = rsqrtf((float)(c + 1));
    h4v sv = h[(size_t)node * 16 + lane];  // self loop (pre-scaled)
    float2 pa = __half22float2(sv.a), pb = __half22float2(sv.b);
    float x0 = pa.x, y0 = pa.y, z0 = pb.x, w0 = pb.y;
    float x1 = 0, y1 = 0, z1 = 0, w1 = 0;
    float x2 = 0, y2 = 0, z2 = 0, w2 = 0;
    float x3 = 0, y3 = 0, z3 = 0, w3 = 0;
    const unsigned short* row = csr + (size_t)node * CAP;
    int j = 0;
    // ---- 8-wide: 8 independent h loads in flight ----
    for (; j + 8 <= c; j += 8) {
        us8 s8 = *(const us8*)(row + j);
        h4v v0 = h[(size_t)s8.a.x * 16 + lane];
        h4v v1 = h[(size_t)s8.a.y * 16 + lane];
        h4v v2 = h[(size_t)s8.a.z * 16 + lane];
        h4v v3 = h[(size_t)s8.a.w * 16 + lane];
        h4v v4 = h[(size_t)s8.b.x * 16 + lane];
        h4v v5 = h[(size_t)s8.b.y * 16 + lane];
        h4v v6 = h[(size_t)s8.b.z * 16 + lane];
        h4v v7 = h[(size_t)s8.b.w * 16 + lane];
        float2 a0 = __half22float2(v0.a), b0 = __half22float2(v0.b);
        float2 a1 = __half22float2(v1.a), b1 = __half22float2(v1.b);
        float2 a2 = __half22float2(v2.a), b2 = __half22float2(v2.b);
        float2 a3 = __half22float2(v3.a), b3 = __half22float2(v3.b);
        x0 += a0.x; y0 += a0.y; z0 += b0.x; w0 += b0.y;
        x1 += a1.x; y1 += a1.y; z1 += b1.x; w1 += b1.y;
        x2 += a2.x; y2 += a2.y; z2 += b2.x; w2 += b2.y;
        x3 += a3.x; y3 += a3.y; z3 += b3.x; w3 += b3.y;
        float2 a4 = __half22float2(v4.a), b4 = __half22float2(v4.b);
        float2 a5 = __half22float2(v5.a), b5 = __half22float2(v5.b);
        float2 a6 = __half22float2(v6.a), b6 = __half22float2(v6.b);
        float2 a7 = __half22float2(v7.a), b7 = __half22float2(v7.b);
        x0 += a4.x; y0 += a4.y; z0 += b4.x; w0 += b4.y;
        x1 += a5.x; y1 += a5.y; z1 += b5.x; w1 += b5.y;
        x2 += a6.x; y2 += a6.y; z2 += b6.x; w2 += b6.y;
        x3 += a7.x; y3 += a7.y; z3 += b7.x; w3 += b7.y;
    }
    // ---- 4-wide remainder ----
    for (; j + 4 <= c; j += 4) {
        ushort4 s4 = *(const ushort4*)(row + j);
        h4v v0 = h[(size_t)s4.x * 16 + lane];
        h4v v1 = h[(size_t)s4.y * 16 + lane];
        h4v v2 = h[(size_t)s4.z * 16 + lane];
        h4v v3 = h[(size_t)s4.w * 16 + lane];
        float2 a0 = __half22float2(v0.a), b0 = __half22float2(v0.b);
        float2 a1 = __half22float2(v1.a), b1 = __half22float2(v1.b);
        float2 a2 = __half22float2(v2.a), b2 = __half22float2(v2.b);
        float2 a3 = __half22float2(v3.a), b3 = __half22float2(v3.b);
        x0 += a0.x; y0 += a0.y; z0 += b0.x; w0 += b0.y;
        x1 += a1.x; y1 += a1.y; z1 += b1.x; w1 += b1.y;
        x2 += a2.x; y2 += a2.y; z2 += b2.x; w2 += b2.y;
        x3 += a3.x; y3 += a3.y; z3 += b3.x; w3 += b3.y;
    }
    // ---- scalar tail ----
    for (; j < c; ++j) {
        h4v v = h[(size_t)row[j] * 16 + lane];
        float2 a = __half22float2(v.a), b = __half22float2(v.b);
        x0 += a.x; y0 += a.y; z0 += b.x; w0 += b.y;
    }
    float sx = (x0 + x1) + (x2 + x3);
    float sy = (y0 + y1) + (y2 + y3);
    float sz = (z0 + z1) + (z2 + z3);
    float sw = (w0 + w1) + (w2 + w3);
    h4v o;
    if (RELU) {
        float4 bv = ((const float4*)bias)[lane];
        float vx = fmaf(sx, di, bv.x); vx = vx > 0.f ? vx : 0.f;
        float vy = fmaf(sy, di, bv.y); vy = vy > 0.f ? vy : 0.f;
        float vz = fmaf(sz, di, bv.z); vz = vz > 0.f ? vz : 0.f;
        float vw = fmaf(sw, di, bv.w); vw = vw > 0.f ? vw : 0.f;
        o.a = __floats2half2_rn(di * vx, di * vy);
        o.b = __floats2half2_rn(di * vz, di * vw);
    } else {
        o.a = __floats2half2_rn(sx * di, sy * di);
        o.b = __floats2half2_rn(sz * di, sw * di);
    }
    out[(size_t)node * 16 + lane] = o;
}

// ---------------- GEMM2 + mean-pool, single pass over full 128 cols ----------------
// Reads z̃ ONCE; W2 fp16 in LDS (16KB) makes the full-width tile fit.

__global__ __launch_bounds__(256) void k_gemm_pool128(
    const __half2* __restrict__ A2,    // z̃ [N][32] half2
    const __half2* __restrict__ w2h,   // [64][64] half2 = [64][128] halves
    const float* __restrict__ bias,    // b2[128]
    const int* __restrict__ batch,
    float* __restrict__ sums, int N) {
    __shared__ __align__(16) float As[64 * 66];
    __shared__ __align__(16) __half2 Wh[64 * 64];   // 16 KB
    __shared__ float red[8][132];
    __shared__ int batchLDS[64];
    const int t = threadIdx.x;
    const int row0 = blockIdx.x * 64;

    for (int idx = t; idx < 4096; idx += 256) Wh[idx] = w2h[idx];
    if (t < 64) batchLDS[t] = batch[min(row0 + t, N - 1)];
    for (int idx = t; idx < 64 * 32; idx += 256) {
        int r = idx >> 5, c2 = idx & 31;
        float2 v = make_float2(0.f, 0.f);
        if (row0 + r < N) v = __half22float2(A2[(size_t)(row0 + r) * 32 + c2]);
        *(float2*)&As[r * 66 + c2 * 2] = v;
    }
    __syncthreads();

    const int tc = (t & 31) * 4;   // 0..124
    const int tr = (t >> 5) * 8;   // 0..56
    float acc[8][4] = {};
#pragma unroll 4
    for (int k = 0; k < 64; k += 2) {
        float2 a[8];
#pragma unroll
        for (int r = 0; r < 8; ++r)
            a[r] = *(const float2*)&As[(tr + r) * 66 + k];
        h4v wv0 = *(const h4v*)&Wh[k * 64 + (tc >> 1)];
        h4v wv1 = *(const h4v*)&Wh[(k + 1) * 64 + (tc >> 1)];
        float2 w00 = __half22float2(wv0.a), w01 = __half22float2(wv0.b);
        float2 w10 = __half22float2(wv1.a), w11 = __half22float2(wv1.b);
#pragma unroll
        for (int r = 0; r < 8; ++r) {
            acc[r][0] = fmaf(a[r].x, w00.x, acc[r][0]);
            acc[r][1] = fmaf(a[r].x, w00.y, acc[r][1]);
            acc[r][2] = fmaf(a[r].x, w01.x, acc[r][2]);
            acc[r][3] = fmaf(a[r].x, w01.y, acc[r][3]);
            acc[r][0] = fmaf(a[r].y, w10.x, acc[r][0]);
            acc[r][1] = fmaf(a[r].y, w10.y, acc[r][1]);
            acc[r][2] = fmaf(a[r].y, w11.x, acc[r][2]);
            acc[r][3] = fmaf(a[r].y, w11.y, acc[r][3]);
        }
    }

    float4 bv = *(const float4*)&bias[tc];
    float v[8][4];
#pragma unroll
    for (int r = 0; r < 8; ++r) {
        bool valid = (row0 + tr + r) < N;
        v[r][0] = valid ? fmaxf(acc[r][0] + bv.x, 0.f) : 0.f;
        v[r][1] = valid ? fmaxf(acc[r][1] + bv.y, 0.f) : 0.f;
        v[r][2] = valid ? fmaxf(acc[r][2] + bv.z, 0.f) : 0.f;
        v[r][3] = valid ? fmaxf(acc[r][3] + bv.w, 0.f) : 0.f;
    }

    const int g0 = batchLDS[0], g1 = batchLDS[63];
    const int rg = t >> 5;
    for (int g = g0; g <= g1; ++g) {
        float p0 = 0.f, p1 = 0.f, p2 = 0.f, p3 = 0.f;
#pragma unroll
        for (int r = 0; r < 8; ++r) {
            if (batchLDS[tr + r] == g) { p0 += v[r][0]; p1 += v[r][1]; p2 += v[r][2]; p3 += v[r][3]; }
        }
        red[rg][tc + 0] = p0; red[rg][tc + 1] = p1;
        red[rg][tc + 2] = p2; red[rg][tc + 3] = p3;
        __syncthreads();
        for (int off = 4; off > 0; off >>= 1) {
            if (rg < off) {
#pragma unroll
                for (int c = 0; c < 4; ++c) red[rg][tc + c] += red[rg + off][tc + c];
            }
            __syncthreads();
        }
        if (rg == 0) {
#pragma unroll
            for (int c = 0; c < 4; ++c)
                atomicAdd(&sums[g * 128 + tc + c], red[0][tc + c]);
        }
        __syncthreads();
    }
}

// ---------------- MLP head: one block per graph (cnt via binary search) ----------------

__global__ void k_mlp(const float* __restrict__ sums, const int* __restrict__ batch, int N,
                      const float* __restrict__ M1, const float* __restrict__ c1,
                      const float* __restrict__ M2, const float* __restrict__ c2,
                      const float* __restrict__ M3, const float* __restrict__ c3,
                      const float* __restrict__ M4, const float* __restrict__ c4,
                      float* __restrict__ out) {
    __shared__ float g[128], t1[64], t2[64], t3[64];
    __shared__ float cntb;
    int b = blockIdx.x;
    int t = threadIdx.x;
    if (t == 0) {
        int lo = 0, hi = N;
        while (lo < hi) { int m = (lo + hi) >> 1; if (batch[m] < b) lo = m + 1; else hi = m; }
        int lb = lo;
        lo = 0; hi = N;
        while (lo < hi) { int m = (lo + hi) >> 1; if (batch[m] <= b) lo = m + 1; else hi = m; }
        cntb = fmaxf((float)(lo - lb), 1.0f);
    }
    __syncthreads();
    if (t < 128) g[t] = sums[b * 128 + t] / cntb;
    __syncthreads();
    if (t < 64) {
        float acc = c1[t];
        for (int k = 0; k < 128; ++k) acc = fmaf(g[k], M1[k * 64 + t], acc);
        t1[t] = acc >= 0.f ? acc : 0.2f * acc;
    }
    __syncthreads();
    if (t < 64) {
        float acc = c2[t];
        for (int k = 0; k < 64; ++k) acc = fmaf(t1[k], M2[k * 64 + t], acc);
        t2[t] = acc >= 0.f ? acc : 0.1f * acc;
    }
    __syncthreads();
    if (t < 64) {
        float acc = c3[t];
        for (int k = 0; k < 64; ++k) acc = fmaf(t2[k], M3[k * 64 + t], acc);
        t3[t] = acc >= 0.f ? acc : 0.1f * acc;
    }
    __syncthreads();
    if (t == 0) {
        float acc = c4[0];
        for (int k = 0; k < 64; ++k) acc = fmaf(t3[k], M4[k], acc);
        out[b] = fmaxf(acc, 0.f);
    }
}

// ---------------- launch ----------------

extern "C" void kernel_launch(void* const* d_in, const int* in_sizes, int n_in,
                              void* d_out, int out_size, void* d_ws, size_t ws_size,
                              hipStream_t stream) {
    const float* x   = (const float*)d_in[0];
    const int*   ei  = (const int*)d_in[1];
    const int*   bat = (const int*)d_in[2];
    const float* W1  = (const float*)d_in[3];
    const float* b1  = (const float*)d_in[4];
    const float* W2  = (const float*)d_in[5];
    const float* b2  = (const float*)d_in[6];
    const float* M1  = (const float*)d_in[7];
    const float* c1  = (const float*)d_in[8];
    const float* M2  = (const float*)d_in[9];
    const float* c2  = (const float*)d_in[10];
    const float* M3  = (const float*)d_in[11];
    const float* c3  = (const float*)d_in[12];
    const float* M4  = (const float*)d_in[13];
    const float* c4  = (const float*)d_in[14];
    float* out = (float*)d_out;

    const int* src = ei;            // edge_index[0]
    const int* dst = ei + N_EDGES;  // edge_index[1]

    // workspace layout
    float* bufA    = (float*)d_ws;                          // g̃ / z̃: N*64 fp16
    float* bufB    = bufA + (size_t)N_NODES * 64;           // h̃1: N*64 fp16
    float* sums    = bufB + (size_t)N_NODES * 64;           // 64*128 f
    int*   cnt     = (int*)(sums + N_GRAPHS * 128);         // N i (degree/slot counter)
    unsigned short* csr = (unsigned short*)(cnt + N_NODES); // N*CAP u16 (fixed-stride rows)
    unsigned* pk   = (unsigned*)(csr + (size_t)N_NODES * CAP); // E u32 packed edges
    __half* w2h    = (__half*)(pk + N_EDGES);               // 64*128 fp16

    // ---- init + pack; ONE-pass CSR build ----
    k_zero_pack<<<(N_EDGES + 255) / 256, 256, 0, stream>>>(cnt, sums, src, dst, pk, W2, w2h);
    k_fill_direct<<<8 * FILL_STRIPES, 256, 0, stream>>>(pk, cnt, csr, N_EDGES);

    const int NBLK = (N_NODES + 63) / 64;   // 782
    const int ABLK = (N_NODES + 15) / 16;   // 3125

    // ---- conv1: g̃(fp16) = dinv ⊙ (x@W1); h̃1(fp16) = dinv ⊙ relu(Â-sum + b1) ----
    k_gemm1<<<NBLK, 256, 0, stream>>>(x, W1, cnt, (__half*)bufA, N_NODES);
    k_agg<true><<<ABLK, 256, 0, stream>>>(
        (const h4v*)bufA, cnt, csr, b1, (h4v*)bufB, N_NODES);

    // ---- conv2: z̃(fp16) = dinv ⊙ (Σ h̃1); single-pass gemm2+relu+mean-pool ----
    k_agg<false><<<ABLK, 256, 0, stream>>>(
        (const h4v*)bufB, cnt, csr, nullptr, (h4v*)bufA, N_NODES);
    k_gemm_pool128<<<NBLK, 256, 0, stream>>>(
        (const __half2*)bufA, (const __half2*)w2h, b2, bat, sums, N_NODES);

    // ---- MLP ----
    k_mlp<<<N_GRAPHS, 128, 0, stream>>>(sums, bat, N_NODES,
                                        M1, c1, M2, c2, M3, c3, M4, c4, out);
}

// Round 8
// 217.043 us; speedup vs baseline: 1.0642x; 1.0321x over previous
//
#include <hip/hip_runtime.h>
#include <hip/hip_fp16.h>

#define N_NODES 50000
#define N_EDGES 800000
#define N_GRAPHS 64

#define CAP 64            // fixed-stride CSR row capacity; P(deg>=64) ~ 1e-13 on Poisson(16)
#define FILL_STRIPES 256  // blocks per node-range; grid = 8*FILL_STRIPES

struct __align__(8)  h4v { __half2 a, b; };          // 4 fp16 = 8 B (gemm_pool W reads)
struct __align__(16) h8v { __half2 a, b, c, d; };    // 8 fp16 = 16 B (gather unit)

// ---------------- init + edge pack + W2->fp16 + graph boundaries ----------------
// pk[e] = (dst<<16)|src : both < 50000 < 65536. One 4B read/edge downstream.
// gend[g] = end index of graph g in sorted batch (replaces mlp binary search).

__global__ void k_zero_pack(int* __restrict__ cnt, float* __restrict__ sums,
                            const int* __restrict__ src, const int* __restrict__ dst,
                            unsigned* __restrict__ pk,
                            const float* __restrict__ W2, __half* __restrict__ w2h,
                            const int* __restrict__ batch, int* __restrict__ gend) {
    int i = blockIdx.x * 256 + threadIdx.x;
    if (i < N_NODES) {
        cnt[i] = 0;
        // sorted batch: boundary -> this node ends its graph. Every graph is
        // populated w.h.p. (~780 nodes each, fixed input), so gend fully written.
        if (i == N_NODES - 1 || batch[i] != batch[i + 1]) gend[batch[i]] = i + 1;
    }
    if (i < N_GRAPHS * 128) sums[i] = 0.f;
    if (i < 64 * 128) w2h[i] = __float2half_rn(W2[i]);
    if (i < N_EDGES) pk[i] = ((unsigned)dst[i] << 16) | (unsigned)src[i];
}

// ---------------- CSR build: ONE pass (fixed-stride rows) ----------------
// slot = atomicAdd(cnt[d]) doubles as degree count. XCD-partitioned:
// cnt lines and csr row destinations stay XCD-local.

__global__ void k_fill_direct(const unsigned* __restrict__ pk, int* __restrict__ cnt,
                              unsigned short* __restrict__ csr, int E) {
    const int range = blockIdx.x & 7;
    const int stripe = blockIdx.x >> 3;
    const unsigned lo = range * (N_NODES / 8);
    const unsigned hi = lo + (N_NODES / 8);
    for (int e = stripe * 256 + threadIdx.x; e < E; e += FILL_STRIPES * 256) {
        unsigned p = pk[e];
        unsigned d = p >> 16;
        if (d >= lo && d < hi) {
            int slot = atomicAdd(&cnt[d], 1);
            if (slot < CAP) csr[(size_t)d * CAP + slot] = (unsigned short)(p & 0xffffu);
        }
    }
}

// ---------------- GEMM1: g̃(fp16) = dinv ⊙ (x @ W1) ----------------
// dinv computed on the fly from cnt (rsqrt of degree+1).

__global__ __launch_bounds__(256) void k_gemm1(const float* __restrict__ A,
                                               const float* __restrict__ W,
                                               const int* __restrict__ cnt,
                                               __half* __restrict__ Cout, int N) {
    const int FIN = 128;
    __shared__ __align__(16) float As[64 * (FIN + 2)];
    __shared__ __align__(16) float Wsm[FIN * 64];
    const int t = threadIdx.x;
    const int row0 = blockIdx.x * 64;

    const int NF4 = 64 * FIN / 4;
    for (int idx = t; idx < NF4; idx += 256) {
        int r = idx / (FIN / 4);
        int c4 = idx % (FIN / 4);
        float4 v = make_float4(0.f, 0.f, 0.f, 0.f);
        if (row0 + r < N) v = ((const float4*)(A + (size_t)(row0 + r) * FIN))[c4];
        float* p = &As[r * (FIN + 2) + c4 * 4];
        ((float2*)p)[0] = make_float2(v.x, v.y);
        ((float2*)p)[1] = make_float2(v.z, v.w);
    }
    for (int idx = t; idx < FIN * 16; idx += 256) {
        int r = idx / 16, c4 = idx % 16;
        *((float4*)&Wsm[r * 64 + c4 * 4]) = ((const float4*)(W + (size_t)r * 64))[c4];
    }
    __syncthreads();

    const int tc = (t & 15) * 4;
    const int tr = (t >> 4) * 4;
    float acc[4][4] = {};
#pragma unroll 4
    for (int k = 0; k < FIN; k += 2) {
        float2 a[4];
#pragma unroll
        for (int r = 0; r < 4; ++r)
            a[r] = *(const float2*)&As[(tr + r) * (FIN + 2) + k];
        float4 w0 = *(const float4*)&Wsm[k * 64 + tc];
        float4 w1 = *(const float4*)&Wsm[(k + 1) * 64 + tc];
#pragma unroll
        for (int r = 0; r < 4; ++r) {
            acc[r][0] = fmaf(a[r].x, w0.x, acc[r][0]);
            acc[r][1] = fmaf(a[r].x, w0.y, acc[r][1]);
            acc[r][2] = fmaf(a[r].x, w0.z, acc[r][2]);
            acc[r][3] = fmaf(a[r].x, w0.w, acc[r][3]);
            acc[r][0] = fmaf(a[r].y, w1.x, acc[r][0]);
            acc[r][1] = fmaf(a[r].y, w1.y, acc[r][1]);
            acc[r][2] = fmaf(a[r].y, w1.z, acc[r][2]);
            acc[r][3] = fmaf(a[r].y, w1.w, acc[r][3]);
        }
    }

#pragma unroll
    for (int r = 0; r < 4; ++r) {
        int row = row0 + tr + r;
        if (row < N) {
            float s = rsqrtf((float)(min(cnt[row], CAP) + 1));
            __half2* dsth = (__half2*)(Cout + (size_t)row * 64 + tc);
            dsth[0] = __floats2half2_rn(acc[r][0] * s, acc[r][1] * s);
            dsth[1] = __floats2half2_rn(acc[r][2] * s, acc[r][3] * s);
        }
    }
}

// ---------------- aggregates: 8 lanes/node, 16 B/lane (dwordx4), 0 LDS ----------------
// h pre-scaled by dinv. R6/R7 lesson: gather is VMEM-instruction/address-bound,
// not BW/latency-bound -> widen per-lane loads to halve instructions per edge.
// A wave covers 8 nodes per load instruction (was 4); unroll-4 keeps 4 rows
// (4KB) in flight per group.

template <bool RELU>
__global__ void k_agg(const h8v* __restrict__ h, const int* __restrict__ cnt,
                      const unsigned short* __restrict__ csr,
                      const float* __restrict__ bias, h8v* __restrict__ out, int N) {
    int node = blockIdx.x * 32 + (threadIdx.x >> 3);
    int lane = threadIdx.x & 7;
    if (node >= N) return;
    int c = min(cnt[node], CAP);
    float di = rsqrtf((float)(c + 1));
    h8v sv = h[(size_t)node * 8 + lane];  // self loop (pre-scaled)
    float2 p0 = __half22float2(sv.a), p1 = __half22float2(sv.b);
    float2 p2 = __half22float2(sv.c), p3 = __half22float2(sv.d);
    // two accumulator chains x 8 features
    float f0 = p0.x, f1 = p0.y, f2 = p1.x, f3 = p1.y;
    float f4 = p2.x, f5 = p2.y, f6 = p3.x, f7 = p3.y;
    float g0 = 0, g1 = 0, g2 = 0, g3 = 0, g4 = 0, g5 = 0, g6 = 0, g7 = 0;
    const unsigned short* row = csr + (size_t)node * CAP;
    int j = 0;
    for (; j + 4 <= c; j += 4) {
        ushort4 s4 = *(const ushort4*)(row + j);   // 8B, broadcast across the 8 lanes
        h8v v0 = h[(size_t)s4.x * 8 + lane];
        h8v v1 = h[(size_t)s4.y * 8 + lane];
        h8v v2 = h[(size_t)s4.z * 8 + lane];
        h8v v3 = h[(size_t)s4.w * 8 + lane];
        float2 a0 = __half22float2(v0.a), a1 = __half22float2(v0.b),
               a2 = __half22float2(v0.c), a3 = __half22float2(v0.d);
        float2 b0 = __half22float2(v1.a), b1 = __half22float2(v1.b),
               b2 = __half22float2(v1.c), b3 = __half22float2(v1.d);
        f0 += a0.x; f1 += a0.y; f2 += a1.x; f3 += a1.y;
        f4 += a2.x; f5 += a2.y; f6 += a3.x; f7 += a3.y;
        g0 += b0.x; g1 += b0.y; g2 += b1.x; g3 += b1.y;
        g4 += b2.x; g5 += b2.y; g6 += b3.x; g7 += b3.y;
        float2 c0 = __half22float2(v2.a), c1 = __half22float2(v2.b),
               c2 = __half22float2(v2.c), c3 = __half22float2(v2.d);
        float2 d0 = __half22float2(v3.a), d1 = __half22float2(v3.b),
               d2 = __half22float2(v3.c), d3 = __half22float2(v3.d);
        f0 += c0.x; f1 += c0.y; f2 += c1.x; f3 += c1.y;
        f4 += c2.x; f5 += c2.y; f6 += c3.x; f7 += c3.y;
        g0 += d0.x; g1 += d0.y; g2 += d1.x; g3 += d1.y;
        g4 += d2.x; g5 += d2.y; g6 += d3.x; g7 += d3.y;
    }
    for (; j < c; ++j) {
        h8v v = h[(size_t)row[j] * 8 + lane];
        float2 a0 = __half22float2(v.a), a1 = __half22float2(v.b),
               a2 = __half22float2(v.c), a3 = __half22float2(v.d);
        f0 += a0.x; f1 += a0.y; f2 += a1.x; f3 += a1.y;
        f4 += a2.x; f5 += a2.y; f6 += a3.x; f7 += a3.y;
    }
    float s0 = f0 + g0, s1 = f1 + g1, s2 = f2 + g2, s3 = f3 + g3;
    float s4 = f4 + g4, s5 = f5 + g5, s6 = f6 + g6, s7 = f7 + g7;
    h8v o;
    if (RELU) {
        float4 bv0 = ((const float4*)bias)[lane * 2];
        float4 bv1 = ((const float4*)bias)[lane * 2 + 1];
        float r0 = fmaf(s0, di, bv0.x); r0 = r0 > 0.f ? r0 : 0.f;
        float r1 = fmaf(s1, di, bv0.y); r1 = r1 > 0.f ? r1 : 0.f;
        float r2 = fmaf(s2, di, bv0.z); r2 = r2 > 0.f ? r2 : 0.f;
        float r3 = fmaf(s3, di, bv0.w); r3 = r3 > 0.f ? r3 : 0.f;
        float r4 = fmaf(s4, di, bv1.x); r4 = r4 > 0.f ? r4 : 0.f;
        float r5 = fmaf(s5, di, bv1.y); r5 = r5 > 0.f ? r5 : 0.f;
        float r6 = fmaf(s6, di, bv1.z); r6 = r6 > 0.f ? r6 : 0.f;
        float r7 = fmaf(s7, di, bv1.w); r7 = r7 > 0.f ? r7 : 0.f;
        o.a = __floats2half2_rn(di * r0, di * r1);
        o.b = __floats2half2_rn(di * r2, di * r3);
        o.c = __floats2half2_rn(di * r4, di * r5);
        o.d = __floats2half2_rn(di * r6, di * r7);
    } else {
        o.a = __floats2half2_rn(s0 * di, s1 * di);
        o.b = __floats2half2_rn(s2 * di, s3 * di);
        o.c = __floats2half2_rn(s4 * di, s5 * di);
        o.d = __floats2half2_rn(s6 * di, s7 * di);
    }
    out[(size_t)node * 8 + lane] = o;
}

// ---------------- GEMM2 + mean-pool, single pass over full 128 cols ----------------
// Reads z̃ ONCE; W2 fp16 in LDS (16KB) makes the full-width tile fit.

__global__ __launch_bounds__(256) void k_gemm_pool128(
    const __half2* __restrict__ A2,    // z̃ [N][32] half2
    const __half2* __restrict__ w2h,   // [64][64] half2 = [64][128] halves
    const float* __restrict__ bias,    // b2[128]
    const int* __restrict__ batch,
    float* __restrict__ sums, int N) {
    __shared__ __align__(16) float As[64 * 66];
    __shared__ __align__(16) __half2 Wh[64 * 64];   // 16 KB
    __shared__ float red[8][132];
    __shared__ int batchLDS[64];
    const int t = threadIdx.x;
    const int row0 = blockIdx.x * 64;

    for (int idx = t; idx < 4096; idx += 256) Wh[idx] = w2h[idx];
    if (t < 64) batchLDS[t] = batch[min(row0 + t, N - 1)];
    for (int idx = t; idx < 64 * 32; idx += 256) {
        int r = idx >> 5, c2 = idx & 31;
        float2 v = make_float2(0.f, 0.f);
        if (row0 + r < N) v = __half22float2(A2[(size_t)(row0 + r) * 32 + c2]);
        *(float2*)&As[r * 66 + c2 * 2] = v;
    }
    __syncthreads();

    const int tc = (t & 31) * 4;   // 0..124
    const int tr = (t >> 5) * 8;   // 0..56
    float acc[8][4] = {};
#pragma unroll 4
    for (int k = 0; k < 64; k += 2) {
        float2 a[8];
#pragma unroll
        for (int r = 0; r < 8; ++r)
            a[r] = *(const float2*)&As[(tr + r) * 66 + k];
        h4v wv0 = *(const h4v*)&Wh[k * 64 + (tc >> 1)];
        h4v wv1 = *(const h4v*)&Wh[(k + 1) * 64 + (tc >> 1)];
        float2 w00 = __half22float2(wv0.a), w01 = __half22float2(wv0.b);
        float2 w10 = __half22float2(wv1.a), w11 = __half22float2(wv1.b);
#pragma unroll
        for (int r = 0; r < 8; ++r) {
            acc[r][0] = fmaf(a[r].x, w00.x, acc[r][0]);
            acc[r][1] = fmaf(a[r].x, w00.y, acc[r][1]);
            acc[r][2] = fmaf(a[r].x, w01.x, acc[r][2]);
            acc[r][3] = fmaf(a[r].x, w01.y, acc[r][3]);
            acc[r][0] = fmaf(a[r].y, w10.x, acc[r][0]);
            acc[r][1] = fmaf(a[r].y, w10.y, acc[r][1]);
            acc[r][2] = fmaf(a[r].y, w11.x, acc[r][2]);
            acc[r][3] = fmaf(a[r].y, w11.y, acc[r][3]);
        }
    }

    float4 bv = *(const float4*)&bias[tc];
    float v[8][4];
#pragma unroll
    for (int r = 0; r < 8; ++r) {
        bool valid = (row0 + tr + r) < N;
        v[r][0] = valid ? fmaxf(acc[r][0] + bv.x, 0.f) : 0.f;
        v[r][1] = valid ? fmaxf(acc[r][1] + bv.y, 0.f) : 0.f;
        v[r][2] = valid ? fmaxf(acc[r][2] + bv.z, 0.f) : 0.f;
        v[r][3] = valid ? fmaxf(acc[r][3] + bv.w, 0.f) : 0.f;
    }

    const int g0 = batchLDS[0], g1 = batchLDS[63];
    const int rg = t >> 5;
    for (int g = g0; g <= g1; ++g) {
        float p0 = 0.f, p1 = 0.f, p2 = 0.f, p3 = 0.f;
#pragma unroll
        for (int r = 0; r < 8; ++r) {
            if (batchLDS[tr + r] == g) { p0 += v[r][0]; p1 += v[r][1]; p2 += v[r][2]; p3 += v[r][3]; }
        }
        red[rg][tc + 0] = p0; red[rg][tc + 1] = p1;
        red[rg][tc + 2] = p2; red[rg][tc + 3] = p3;
        __syncthreads();
        for (int off = 4; off > 0; off >>= 1) {
            if (rg < off) {
#pragma unroll
                for (int c = 0; c < 4; ++c) red[rg][tc + c] += red[rg + off][tc + c];
            }
            __syncthreads();
        }
        if (rg == 0) {
#pragma unroll
            for (int c = 0; c < 4; ++c)
                atomicAdd(&sums[g * 128 + tc + c], red[0][tc + c]);
        }
        __syncthreads();
    }
}

// ---------------- MLP head: one block per graph (counts precomputed) ----------------

__global__ void k_mlp(const float* __restrict__ sums, const int* __restrict__ gend,
                      const float* __restrict__ M1, const float* __restrict__ c1,
                      const float* __restrict__ M2, const float* __restrict__ c2,
                      const float* __restrict__ M3, const float* __restrict__ c3,
                      const float* __restrict__ M4, const float* __restrict__ c4,
                      float* __restrict__ out) {
    __shared__ float g[128], t1[64], t2[64], t3[64];
    __shared__ float cntb;
    int b = blockIdx.x;
    int t = threadIdx.x;
    if (t == 0) {
        int lb = (b > 0) ? gend[b - 1] : 0;
        cntb = fmaxf((float)(gend[b] - lb), 1.0f);
    }
    __syncthreads();
    if (t < 128) g[t] = sums[b * 128 + t] / cntb;
    __syncthreads();
    if (t < 64) {
        float acc = c1[t];
        for (int k = 0; k < 128; ++k) acc = fmaf(g[k], M1[k * 64 + t], acc);
        t1[t] = acc >= 0.f ? acc : 0.2f * acc;
    }
    __syncthreads();
    if (t < 64) {
        float acc = c2[t];
        for (int k = 0; k < 64; ++k) acc = fmaf(t1[k], M2[k * 64 + t], acc);
        t2[t] = acc >= 0.f ? acc : 0.1f * acc;
    }
    __syncthreads();
    if (t < 64) {
        float acc = c3[t];
        for (int k = 0; k < 64; ++k) acc = fmaf(t2[k], M3[k * 64 + t], acc);
        t3[t] = acc >= 0.f ? acc : 0.1f * acc;
    }
    __syncthreads();
    if (t == 0) {
        float acc = c4[0];
        for (int k = 0; k < 64; ++k) acc = fmaf(t3[k], M4[k], acc);
        out[b] = fmaxf(acc, 0.f);
    }
}

// ---------------- launch ----------------

extern "C" void kernel_launch(void* const* d_in, const int* in_sizes, int n_in,
                              void* d_out, int out_size, void* d_ws, size_t ws_size,
                              hipStream_t stream) {
    const float* x   = (const float*)d_in[0];
    const int*   ei  = (const int*)d_in[1];
    const int*   bat = (const int*)d_in[2];
    const float* W1  = (const float*)d_in[3];
    const float* b1  = (const float*)d_in[4];
    const float* W2  = (const float*)d_in[5];
    const float* b2  = (const float*)d_in[6];
    const float* M1  = (const float*)d_in[7];
    const float* c1  = (const float*)d_in[8];
    const float* M2  = (const float*)d_in[9];
    const float* c2  = (const float*)d_in[10];
    const float* M3  = (const float*)d_in[11];
    const float* c3  = (const float*)d_in[12];
    const float* M4  = (const float*)d_in[13];
    const float* c4  = (const float*)d_in[14];
    float* out = (float*)d_out;

    const int* src = ei;            // edge_index[0]
    const int* dst = ei + N_EDGES;  // edge_index[1]

    // workspace layout
    float* bufA    = (float*)d_ws;                          // g̃ / z̃: N*64 fp16
    float* bufB    = bufA + (size_t)N_NODES * 64;           // h̃1: N*64 fp16
    float* sums    = bufB + (size_t)N_NODES * 64;           // 64*128 f
    int*   cnt     = (int*)(sums + N_GRAPHS * 128);         // N i (degree/slot counter)
    unsigned short* csr = (unsigned short*)(cnt + N_NODES); // N*CAP u16 (fixed-stride rows)
    unsigned* pk   = (unsigned*)(csr + (size_t)N_NODES * CAP); // E u32 packed edges
    __half* w2h    = (__half*)(pk + N_EDGES);               // 64*128 fp16
    int*   gend    = (int*)(w2h + 64 * 128);                // 64 i (graph end indices)

    // ---- init + pack + graph boundaries; ONE-pass CSR build ----
    k_zero_pack<<<(N_EDGES + 255) / 256, 256, 0, stream>>>(cnt, sums, src, dst, pk,
                                                           W2, w2h, bat, gend);
    k_fill_direct<<<8 * FILL_STRIPES, 256, 0, stream>>>(pk, cnt, csr, N_EDGES);

    const int NBLK = (N_NODES + 63) / 64;   // 782
    const int ABLK = (N_NODES + 31) / 32;   // 1563 (8 lanes/node, 32 nodes/block)

    // ---- conv1: g̃(fp16) = dinv ⊙ (x@W1); h̃1(fp16) = dinv ⊙ relu(Â-sum + b1) ----
    k_gemm1<<<NBLK, 256, 0, stream>>>(x, W1, cnt, (__half*)bufA, N_NODES);
    k_agg<true><<<ABLK, 256, 0, stream>>>(
        (const h8v*)bufA, cnt, csr, b1, (h8v*)bufB, N_NODES);

    // ---- conv2: z̃(fp16) = dinv ⊙ (Σ h̃1); single-pass gemm2+relu+mean-pool ----
    k_agg<false><<<ABLK, 256, 0, stream>>>(
        (const h8v*)bufB, cnt, csr, nullptr, (h8v*)bufA, N_NODES);
    k_gemm_pool128<<<NBLK, 256, 0, stream>>>(
        (const __half2*)bufA, (const __half2*)w2h, b2, bat, sums, N_NODES);

    // ---- MLP ----
    k_mlp<<<N_GRAPHS, 128, 0, stream>>>(sums, gend,
                                        M1, c1, M2, c2, M3, c3, M4, c4, out);
}